// Round 9
// baseline (104.696 us; speedup 1.0000x reference)
//
#include <hip/hip_runtime.h>
#include <hip/hip_bf16.h>
#include <stdint.h>

#define LOG2E 1.44269504f
#define NROWS 8192

using bf16x8 = __attribute__((ext_vector_type(8))) short;
using f32x4  = __attribute__((ext_vector_type(4))) float;

__device__ __forceinline__ unsigned short f2bf(float f) {
    unsigned u = __float_as_uint(f);
    u += 0x7fff + ((u >> 16) & 1);          // RNE
    return (unsigned short)(u >> 16);
}
__device__ __forceinline__ unsigned cvt_pk_bf16(float lo, float hi) {
    unsigned r;
    asm("v_cvt_pk_bf16_f32 %0, %1, %2" : "=v"(r) : "v"(lo), "v"(hi));
    return r;
}
__device__ __forceinline__ float fast_exp2(float x) { return __builtin_amdgcn_exp2f(x); }

#define MFMA __builtin_amdgcn_mfma_f32_16x16x32_bf16

// ---------------------------------------------------------------------------
// Setup (round-5 verbatim, VERIFIED): pack adjacency bits, bf16 weights,
// pad x, precompute Wsd. Grid 1024 x 256.
// ---------------------------------------------------------------------------
__global__ __launch_bounds__(256) void setup_kernel(
    const float* __restrict__ x, const int* __restrict__ adj, const float* __restrict__ h_prev,
    const float* __restrict__ W0, const float* __restrict__ as0, const float* __restrict__ ad0,
    const float* __restrict__ W1, const float* __restrict__ as1, const float* __restrict__ ad1,
    const float* __restrict__ W2, const float* __restrict__ as2, const float* __restrict__ ad2,
    const float* __restrict__ gwi, const float* __restrict__ gwh,
    const float* __restrict__ Wa1, const float* __restrict__ Wc1,
    unsigned long long* __restrict__ maskbits, unsigned short* __restrict__ xpad,
    unsigned short* __restrict__ hp16,
    unsigned short* __restrict__ W0Tp, unsigned short* __restrict__ W1T, unsigned short* __restrict__ W2T,
    unsigned short* __restrict__ wi16, unsigned short* __restrict__ wh16,
    unsigned short* __restrict__ Wa1T, unsigned short* __restrict__ Wc1T,
    unsigned short* __restrict__ Wsd0, unsigned short* __restrict__ Wsd1, unsigned short* __restrict__ Wsd2)
{
    int tid  = blockIdx.x * 256 + threadIdx.x;   // 0 .. 262143
    int lane = threadIdx.x & 63;
    int wv   = tid >> 6;

    #pragma unroll
    for (int i = 0; i < 4; ++i) {
        int w   = wv * 4 + i;
        int row = w >> 4, wc = w & 15;
        int j   = wc * 64 + lane;
        unsigned long long m = __ballot(adj[row * 1024 + j] > 0);
        if (lane == 0) maskbits[w] = m;
    }
    {
        int n = tid >> 5, k = tid & 31;
        xpad[tid] = (k < 3) ? f2bf(x[n * 3 + k]) : (unsigned short)0;
    }
    hp16[tid]          = f2bf(h_prev[tid]);
    hp16[tid + 262144] = f2bf(h_prev[tid + 262144]);
    if (tid < 12288) {
        int n = tid >> 6, k = tid & 63;
        W1T[tid]  = f2bf(W1[k * 192 + n]);
        W2T[tid]  = f2bf(W2[k * 192 + n]);
        wi16[tid] = f2bf(gwi[tid]);
        wh16[tid] = f2bf(gwh[tid]);
    }
    if (tid < 6144) {
        int n = tid >> 5, k = tid & 31;
        W0Tp[tid] = (k < 3) ? f2bf(W0[k * 192 + n]) : (unsigned short)0;
    }
    if (tid < 2048) {
        int n = tid >> 6, k = tid & 63;
        Wa1T[tid] = f2bf(Wa1[k * 32 + n]);
        Wc1T[tid] = f2bf(Wc1[k * 32 + n]);
    }
    if (tid < 16 * 32) {
        int c = tid >> 5, k = tid & 31;
        float v = 0.f;
        if (c < 6 && k < 3) {
            int h = c >> 1; const float* a = (c & 1) ? ad0 : as0;
            for (int f = 0; f < 64; ++f) v += W0[k * 192 + h * 64 + f] * a[h * 64 + f];
        }
        Wsd0[tid] = f2bf(v);
    }
    if (tid < 16 * 64) {
        int c = tid >> 6, k = tid & 63;
        float v1 = 0.f, v2 = 0.f;
        if (c < 6) {
            int h = c >> 1;
            const float* a1 = (c & 1) ? ad1 : as1;
            const float* a2 = (c & 1) ? ad2 : as2;
            for (int f = 0; f < 64; ++f) {
                v1 += W1[k * 192 + h * 64 + f] * a1[h * 64 + f];
                v2 += W2[k * 192 + h * 64 + f] * a2[h * 64 + f];
            }
        }
        Wsd1[tid] = f2bf(v1);
        Wsd2[tid] = f2bf(v2);
    }
}

// ---------------------------------------------------------------------------
// Projection (round-5 verbatim, VERIFIED as <32,0>). Grid 512 x 256.
// ---------------------------------------------------------------------------
template<int KDIM, int MODE>
__global__ __launch_bounds__(256) void proj_kernel(
    const unsigned short* __restrict__ A16,
    const float* __restrict__ haccp,
    float* __restrict__ rsum,
    const unsigned short* __restrict__ WT,    // [192][KDIM]
    const unsigned short* __restrict__ WsdT,  // [16][KDIM]
    unsigned short* __restrict__ VT,
    float* __restrict__ st, float* __restrict__ dt)
{
    int b     = blockIdx.x & 7;
    int nbase = (int)(blockIdx.x >> 3) << 4;
    int fg = threadIdx.x >> 6, l = threadIdx.x & 63;
    int l15 = l & 15, l4 = l >> 4;
    int row = b * 1024 + nbase + l15;
    constexpr int NK = KDIM / 32;

    bf16x8 afr[NK];
    if constexpr (MODE == 0) {
        #pragma unroll
        for (int ks = 0; ks < NK; ++ks)
            afr[ks] = *(const bf16x8*)(A16 + (size_t)row * KDIM + ks * 32 + l4 * 8);
    } else {
        float sf[2][8];
        #pragma unroll
        for (int ks = 0; ks < 2; ++ks) {
            int fb = ks * 32 + l4 * 8;
            const float* hp = haccp + (size_t)row * 192 + fb;
            float4 a0 = *(const float4*)(hp);       float4 a1 = *(const float4*)(hp + 4);
            float4 c0 = *(const float4*)(hp + 64);  float4 c1 = *(const float4*)(hp + 68);
            float4 e0 = *(const float4*)(hp + 128); float4 e1 = *(const float4*)(hp + 132);
            float m[8] = {a0.x + c0.x + e0.x, a0.y + c0.y + e0.y, a0.z + c0.z + e0.z, a0.w + c0.w + e0.w,
                          a1.x + c1.x + e1.x, a1.y + c1.y + e1.y, a1.z + c1.z + e1.z, a1.w + c1.w + e1.w};
            float r[8] = {0.f,0.f,0.f,0.f,0.f,0.f,0.f,0.f};
            if constexpr (MODE == 2) {
                const float* rp = rsum + (size_t)row * 64 + fb;
                float4 r0 = *(const float4*)(rp); float4 r1 = *(const float4*)(rp + 4);
                r[0]=r0.x; r[1]=r0.y; r[2]=r0.z; r[3]=r0.w;
                r[4]=r1.x; r[5]=r1.y; r[6]=r1.z; r[7]=r1.w;
            }
            #pragma unroll
            for (int j = 0; j < 8; ++j) {
                float v = m[j] * (1.f / 3.f);
                v = (v > 0.f) ? v : (fast_exp2(v * LOG2E) - 1.f);
                sf[ks][j] = v + r[j];
            }
        }
        __syncthreads();
        if (fg == 0) {
            #pragma unroll
            for (int ks = 0; ks < 2; ++ks) {
                float* rp = rsum + (size_t)row * 64 + ks * 32 + l4 * 8;
                *(float4*)(rp)     = make_float4(sf[ks][0], sf[ks][1], sf[ks][2], sf[ks][3]);
                *(float4*)(rp + 4) = make_float4(sf[ks][4], sf[ks][5], sf[ks][6], sf[ks][7]);
            }
        }
        #pragma unroll
        for (int ks = 0; ks < 2; ++ks) {
            union { unsigned u[4]; bf16x8 v; } uu;
            #pragma unroll
            for (int jj = 0; jj < 4; ++jj)
                uu.u[jj] = cvt_pk_bf16(sf[ks][2 * jj], sf[ks][2 * jj + 1]);
            afr[ks] = uu.v;
        }
    }

    f32x4 acc[3] = {(f32x4)0.f, (f32x4)0.f, (f32x4)0.f};
    f32x4 sdacc  = (f32x4)0.f;
    #pragma unroll
    for (int ks = 0; ks < NK; ++ks) {
        int k = ks * 32 + l4 * 8;
        #pragma unroll
        for (int t = 0; t < 3; ++t) {
            int n = (fg * 3 + t) * 16 + l15;
            bf16x8 bf = *(const bf16x8*)(WT + (size_t)n * KDIM + k);
            acc[t] = MFMA(afr[ks], bf, acc[t], 0, 0, 0);
        }
        if (fg == 0) {
            bf16x8 bsd = *(const bf16x8*)(WsdT + (size_t)l15 * KDIM + k);
            sdacc = MFMA(afr[ks], bsd, sdacc, 0, 0, 0);
        }
    }
    #pragma unroll
    for (int t = 0; t < 3; ++t) {
        int hf = (fg * 3 + t) * 16 + l15;
        size_t base = ((size_t)(b * 3 + (hf >> 6)) * 64 + (hf & 63)) * 1024 + nbase + l4 * 4;
        uint2 pk;
        pk.x = cvt_pk_bf16(acc[t][0], acc[t][1]);
        pk.y = cvt_pk_bf16(acc[t][2], acc[t][3]);
        *(uint2*)(VT + base) = pk;
    }
    if (fg == 0 && l15 < 6) {
        int h = l15 >> 1;
        float* dst = (l15 & 1) ? dt : st;
        size_t base = (size_t)(b * 3 + h) * 1024 + nbase + l4 * 4;
        #pragma unroll
        for (int r = 0; r < 4; ++r) dst[base + r] = sdacc[r];
    }
}

// ---------------------------------------------------------------------------
// Fused layer kernel (round-6/8 verbatim): attn (3 heads, 16 rows) +
// combine + next-layer proj. MODE 1: rsum := sf; MODE 2: sf += rsum, rsum := sf.
// ---------------------------------------------------------------------------
template<int MODE>
__global__ __launch_bounds__(512, 4) void fused_kernel(
    const unsigned short* __restrict__ VTin,
    const float* __restrict__ stin, const float* __restrict__ dtin,
    const unsigned int* __restrict__ maskw,
    const unsigned short* __restrict__ WT,
    const unsigned short* __restrict__ WsdT,
    float* __restrict__ rsum,
    unsigned short* __restrict__ VTout, float* __restrict__ stout, float* __restrict__ dtout)
{
    __shared__ float F1lds[1024];
    __shared__ float F2lds[1024];
    __shared__ unsigned int lmask[16 * 33];
    __shared__ float pO[8][16 * 68];
    __shared__ float pZ[8][16];
    __shared__ float hlds[16][196];

    int bb = blockIdx.x;
    int b = bb & 7, nbase = (bb >> 3) << 4;
    int tid = threadIdx.x;
    int w = tid >> 6, l = tid & 63;
    int l15 = l & 15, l4 = l >> 4;

    { int r = tid >> 5, wd = tid & 31;
      lmask[r * 33 + wd] = maskw[(size_t)(nbase + r) * 32 + wd]; }

    for (int h = 0; h < 3; ++h) {
        int bh = b * 3 + h;
        __syncthreads();
        { int j2 = tid * 2;
          float2 dv = *(const float2*)(dtin + (size_t)bh * 1024 + j2);
          F1lds[j2]     = fast_exp2(dv.x * LOG2E);
          F1lds[j2 + 1] = fast_exp2(dv.y * LOG2E);
          F2lds[j2]     = fast_exp2(dv.x * (0.2f * LOG2E));
          F2lds[j2 + 1] = fast_exp2(dv.y * (0.2f * LOG2E)); }
        __syncthreads();

        float R = fast_exp2(stin[(size_t)bh * 1024 + nbase + l15] * (-0.8f * LOG2E));
        const unsigned short* vbase = VTin + (size_t)bh * 64 * 1024;
        f32x4 a0 = (f32x4)0.f, a1 = (f32x4)0.f, a2 = (f32x4)0.f, a3 = (f32x4)0.f;
        float z = 0.f;
        int jb = w * 128;

        float4 pA0, pB0, qA0, qB0, pA1, pB1, qA1, qB1;
        bf16x8 vA0, vB0, vC0, vD0, vA1, vB1, vC1, vD1;
        auto LD = [&](int it, float4& pA, float4& pB, float4& qA, float4& qB,
                      bf16x8& Va, bf16x8& Vb, bf16x8& Vc, bf16x8& Vd) {
            int kk = jb + it * 32 + l4 * 8;
            pA = *(const float4*)(F1lds + kk);
            pB = *(const float4*)(F1lds + kk + 4);
            qA = *(const float4*)(F2lds + kk);
            qB = *(const float4*)(F2lds + kk + 4);
            Va = *(const bf16x8*)(vbase + (size_t)(l15)      * 1024 + kk);
            Vb = *(const bf16x8*)(vbase + (size_t)(16 + l15) * 1024 + kk);
            Vc = *(const bf16x8*)(vbase + (size_t)(32 + l15) * 1024 + kk);
            Vd = *(const bf16x8*)(vbase + (size_t)(48 + l15) * 1024 + kk);
        };
        auto CS = [&](int it, float4 pA, float4 pB, float4 qA, float4 qB,
                      bf16x8 Va, bf16x8 Vb, bf16x8 Vc, bf16x8 Vd) {
            unsigned m = (lmask[l15 * 33 + (w << 2) + it] >> (l4 * 8)) & 0xffu;
            float f1[8] = {pA.x, pA.y, pA.z, pA.w, pB.x, pB.y, pB.z, pB.w};
            float f2[8] = {qA.x, qA.y, qA.z, qA.w, qB.x, qB.y, qB.z, qB.w};
            float pv[8];
            #pragma unroll
            for (int j = 0; j < 8; ++j) {
                float t = fmaxf(f1[j], R * f2[j]);
                pv[j] = ((m >> j) & 1) ? t : 0.f;
                z += pv[j];
            }
            union { unsigned u[4]; bf16x8 v; } ua;
            #pragma unroll
            for (int jj = 0; jj < 4; ++jj) ua.u[jj] = cvt_pk_bf16(pv[2 * jj], pv[2 * jj + 1]);
            a0 = MFMA(ua.v, Va, a0, 0, 0, 0);
            a1 = MFMA(ua.v, Vb, a1, 0, 0, 0);
            a2 = MFMA(ua.v, Vc, a2, 0, 0, 0);
            a3 = MFMA(ua.v, Vd, a3, 0, 0, 0);
        };
        LD(0, pA0, pB0, qA0, qB0, vA0, vB0, vC0, vD0);
        LD(1, pA1, pB1, qA1, qB1, vA1, vB1, vC1, vD1);
        CS(0, pA0, pB0, qA0, qB0, vA0, vB0, vC0, vD0);
        LD(2, pA0, pB0, qA0, qB0, vA0, vB0, vC0, vD0);
        CS(1, pA1, pB1, qA1, qB1, vA1, vB1, vC1, vD1);
        LD(3, pA1, pB1, qA1, qB1, vA1, vB1, vC1, vD1);
        CS(2, pA0, pB0, qA0, qB0, vA0, vB0, vC0, vD0);
        CS(3, pA1, pB1, qA1, qB1, vA1, vB1, vC1, vD1);

        z += __shfl_xor(z, 16); z += __shfl_xor(z, 32);
        if (l < 16) pZ[w][l] = z;
        #pragma unroll
        for (int r = 0; r < 4; ++r) {
            pO[w][(l4 * 4 + r) * 68 + l15]      = a0[r];
            pO[w][(l4 * 4 + r) * 68 + 16 + l15] = a1[r];
            pO[w][(l4 * 4 + r) * 68 + 32 + l15] = a2[r];
            pO[w][(l4 * 4 + r) * 68 + 48 + l15] = a3[r];
        }
        __syncthreads();
        { int crow = tid >> 5, cc = (tid & 31) * 2;
          float o0 = 0.f, o1 = 0.f, zz = 0.f;
          #pragma unroll
          for (int ww = 0; ww < 8; ++ww) {
              o0 += pO[ww][crow * 68 + cc];
              o1 += pO[ww][crow * 68 + cc + 1];
              zz += pZ[ww][crow];
          }
          float rcp = 1.f / ((zz == 0.f) ? 1.f : zz);
          hlds[crow][h * 64 + cc]     = o0 * rcp;
          hlds[crow][h * 64 + cc + 1] = o1 * rcp; }
    }
    __syncthreads();

    int arow = b * 1024 + nbase + l15;
    float sfv[2][8];
    #pragma unroll
    for (int ks = 0; ks < 2; ++ks) {
        int fb = ks * 32 + l4 * 8;
        float4 m0a = *(const float4*)(&hlds[l15][fb]);
        float4 m0b = *(const float4*)(&hlds[l15][fb + 4]);
        float4 m1a = *(const float4*)(&hlds[l15][64 + fb]);
        float4 m1b = *(const float4*)(&hlds[l15][64 + fb + 4]);
        float4 m2a = *(const float4*)(&hlds[l15][128 + fb]);
        float4 m2b = *(const float4*)(&hlds[l15][128 + fb + 4]);
        float mv[8] = {m0a.x + m1a.x + m2a.x, m0a.y + m1a.y + m2a.y,
                       m0a.z + m1a.z + m2a.z, m0a.w + m1a.w + m2a.w,
                       m0b.x + m1b.x + m2b.x, m0b.y + m1b.y + m2b.y,
                       m0b.z + m1b.z + m2b.z, m0b.w + m1b.w + m2b.w};
        float rr[8] = {0.f, 0.f, 0.f, 0.f, 0.f, 0.f, 0.f, 0.f};
        if constexpr (MODE == 2) {
            const float* rp = rsum + (size_t)arow * 64 + fb;
            float4 r0 = *(const float4*)(rp);
            float4 r1 = *(const float4*)(rp + 4);
            rr[0] = r0.x; rr[1] = r0.y; rr[2] = r0.z; rr[3] = r0.w;
            rr[4] = r1.x; rr[5] = r1.y; rr[6] = r1.z; rr[7] = r1.w;
        }
        #pragma unroll
        for (int j = 0; j < 8; ++j) {
            float v = mv[j] * (1.f / 3.f);
            v = (v > 0.f) ? v : (fast_exp2(v * LOG2E) - 1.f);
            sfv[ks][j] = v + rr[j];
        }
    }
    __syncthreads();
    if (w == 0) {
        #pragma unroll
        for (int ks = 0; ks < 2; ++ks) {
            float* rp = rsum + (size_t)arow * 64 + ks * 32 + l4 * 8;
            *(float4*)(rp)     = make_float4(sfv[ks][0], sfv[ks][1], sfv[ks][2], sfv[ks][3]);
            *(float4*)(rp + 4) = make_float4(sfv[ks][4], sfv[ks][5], sfv[ks][6], sfv[ks][7]);
        }
    }
    bf16x8 afr[2];
    #pragma unroll
    for (int ks = 0; ks < 2; ++ks) {
        union { unsigned u[4]; bf16x8 v; } uu;
        #pragma unroll
        for (int jj = 0; jj < 4; ++jj)
            uu.u[jj] = cvt_pk_bf16(sfv[ks][2 * jj], sfv[ks][2 * jj + 1]);
        afr[ks] = uu.v;
    }

    f32x4 pc0 = (f32x4)0.f, pc1 = (f32x4)0.f, sd = (f32x4)0.f;
    #pragma unroll
    for (int ks = 0; ks < 2; ++ks) {
        int k = ks * 32 + l4 * 8;
        bf16x8 b0 = *(const bf16x8*)(WT + (size_t)(w * 16 + l15) * 64 + k);
        pc0 = MFMA(afr[ks], b0, pc0, 0, 0, 0);
        if (w < 4) {
            bf16x8 b1 = *(const bf16x8*)(WT + (size_t)((w + 8) * 16 + l15) * 64 + k);
            pc1 = MFMA(afr[ks], b1, pc1, 0, 0, 0);
        }
        if (w == 4) {
            bf16x8 bs = *(const bf16x8*)(WsdT + (size_t)l15 * 64 + k);
            sd = MFMA(afr[ks], bs, sd, 0, 0, 0);
        }
    }
    auto writeVT = [&](int f, f32x4 a) {
        int hf = f * 16 + l15;
        size_t base = ((size_t)(b * 3 + (hf >> 6)) * 64 + (hf & 63)) * 1024 + nbase + l4 * 4;
        uint2 pk; pk.x = cvt_pk_bf16(a[0], a[1]); pk.y = cvt_pk_bf16(a[2], a[3]);
        *(uint2*)(VTout + base) = pk;
    };
    writeVT(w, pc0);
    if (w < 4) writeVT(w + 8, pc1);
    if (w == 4 && l15 < 6) {
        int hh = l15 >> 1;
        float* dstp = (l15 & 1) ? dtout : stout;
        size_t base = (size_t)(b * 3 + hh) * 1024 + nbase + l4 * 4;
        #pragma unroll
        for (int r = 0; r < 4; ++r) dstp[base + r] = sd[r];
    }
}

// ---------------------------------------------------------------------------
// F2G (round-6/8 verbatim): attn layer2 + combine + GRU + heads.
// ---------------------------------------------------------------------------
__global__ __launch_bounds__(512, 4) void f2g_kernel(
    const unsigned short* __restrict__ VTin,
    const float* __restrict__ stin, const float* __restrict__ dtin,
    const unsigned int* __restrict__ maskw,
    const float* __restrict__ rsum,
    const float* __restrict__ hprev,
    const unsigned short* __restrict__ wi16, const unsigned short* __restrict__ wh16,
    const float* __restrict__ bi, const float* __restrict__ bh_,
    const unsigned short* __restrict__ Wa1T, const unsigned short* __restrict__ Wc1T,
    const float* __restrict__ ba1, const float* __restrict__ Wa2, const float* __restrict__ ba2,
    const float* __restrict__ bc1, const float* __restrict__ Wc2, const float* __restrict__ bc2,
    float* __restrict__ hnew, float* __restrict__ probs, float* __restrict__ value)
{
    __shared__ float F1lds[1024];
    __shared__ float F2lds[1024];
    __shared__ unsigned int lmask[16 * 33];
    __shared__ float pO[8][16 * 68];
    __shared__ float pZ[8][16];
    __shared__ float hlds[16][196];
    __shared__ unsigned short hnlds[16 * 72];

    int bb = blockIdx.x;
    int b = bb & 7, nbase = (bb >> 3) << 4;
    int tid = threadIdx.x;
    int w = tid >> 6, l = tid & 63;
    int l15 = l & 15, l4 = l >> 4;

    { int r = tid >> 5, wd = tid & 31;
      lmask[r * 33 + wd] = maskw[(size_t)(nbase + r) * 32 + wd]; }

    for (int h = 0; h < 3; ++h) {
        int bh = b * 3 + h;
        __syncthreads();
        { int j2 = tid * 2;
          float2 dv = *(const float2*)(dtin + (size_t)bh * 1024 + j2);
          F1lds[j2]     = fast_exp2(dv.x * LOG2E);
          F1lds[j2 + 1] = fast_exp2(dv.y * LOG2E);
          F2lds[j2]     = fast_exp2(dv.x * (0.2f * LOG2E));
          F2lds[j2 + 1] = fast_exp2(dv.y * (0.2f * LOG2E)); }
        __syncthreads();

        float R = fast_exp2(stin[(size_t)bh * 1024 + nbase + l15] * (-0.8f * LOG2E));
        const unsigned short* vbase = VTin + (size_t)bh * 64 * 1024;
        f32x4 a0 = (f32x4)0.f, a1 = (f32x4)0.f, a2 = (f32x4)0.f, a3 = (f32x4)0.f;
        float z = 0.f;
        int jb = w * 128;

        float4 pA0, pB0, qA0, qB0, pA1, pB1, qA1, qB1;
        bf16x8 vA0, vB0, vC0, vD0, vA1, vB1, vC1, vD1;
        auto LD = [&](int it, float4& pA, float4& pB, float4& qA, float4& qB,
                      bf16x8& Va, bf16x8& Vb, bf16x8& Vc, bf16x8& Vd) {
            int kk = jb + it * 32 + l4 * 8;
            pA = *(const float4*)(F1lds + kk);
            pB = *(const float4*)(F1lds + kk + 4);
            qA = *(const float4*)(F2lds + kk);
            qB = *(const float4*)(F2lds + kk + 4);
            Va = *(const bf16x8*)(vbase + (size_t)(l15)      * 1024 + kk);
            Vb = *(const bf16x8*)(vbase + (size_t)(16 + l15) * 1024 + kk);
            Vc = *(const bf16x8*)(vbase + (size_t)(32 + l15) * 1024 + kk);
            Vd = *(const bf16x8*)(vbase + (size_t)(48 + l15) * 1024 + kk);
        };
        auto CS = [&](int it, float4 pA, float4 pB, float4 qA, float4 qB,
                      bf16x8 Va, bf16x8 Vb, bf16x8 Vc, bf16x8 Vd) {
            unsigned m = (lmask[l15 * 33 + (w << 2) + it] >> (l4 * 8)) & 0xffu;
            float f1[8] = {pA.x, pA.y, pA.z, pA.w, pB.x, pB.y, pB.z, pB.w};
            float f2[8] = {qA.x, qA.y, qA.z, qA.w, qB.x, qB.y, qB.z, qB.w};
            float pv[8];
            #pragma unroll
            for (int j = 0; j < 8; ++j) {
                float t = fmaxf(f1[j], R * f2[j]);
                pv[j] = ((m >> j) & 1) ? t : 0.f;
                z += pv[j];
            }
            union { unsigned u[4]; bf16x8 v; } ua;
            #pragma unroll
            for (int jj = 0; jj < 4; ++jj) ua.u[jj] = cvt_pk_bf16(pv[2 * jj], pv[2 * jj + 1]);
            a0 = MFMA(ua.v, Va, a0, 0, 0, 0);
            a1 = MFMA(ua.v, Vb, a1, 0, 0, 0);
            a2 = MFMA(ua.v, Vc, a2, 0, 0, 0);
            a3 = MFMA(ua.v, Vd, a3, 0, 0, 0);
        };
        LD(0, pA0, pB0, qA0, qB0, vA0, vB0, vC0, vD0);
        LD(1, pA1, pB1, qA1, qB1, vA1, vB1, vC1, vD1);
        CS(0, pA0, pB0, qA0, qB0, vA0, vB0, vC0, vD0);
        LD(2, pA0, pB0, qA0, qB0, vA0, vB0, vC0, vD0);
        CS(1, pA1, pB1, qA1, qB1, vA1, vB1, vC1, vD1);
        LD(3, pA1, pB1, qA1, qB1, vA1, vB1, vC1, vD1);
        CS(2, pA0, pB0, qA0, qB0, vA0, vB0, vC0, vD0);
        CS(3, pA1, pB1, qA1, qB1, vA1, vB1, vC1, vD1);

        z += __shfl_xor(z, 16); z += __shfl_xor(z, 32);
        if (l < 16) pZ[w][l] = z;
        #pragma unroll
        for (int r = 0; r < 4; ++r) {
            pO[w][(l4 * 4 + r) * 68 + l15]      = a0[r];
            pO[w][(l4 * 4 + r) * 68 + 16 + l15] = a1[r];
            pO[w][(l4 * 4 + r) * 68 + 32 + l15] = a2[r];
            pO[w][(l4 * 4 + r) * 68 + 48 + l15] = a3[r];
        }
        __syncthreads();
        { int crow = tid >> 5, cc = (tid & 31) * 2;
          float o0 = 0.f, o1 = 0.f, zz = 0.f;
          #pragma unroll
          for (int ww = 0; ww < 8; ++ww) {
              o0 += pO[ww][crow * 68 + cc];
              o1 += pO[ww][crow * 68 + cc + 1];
              zz += pZ[ww][crow];
          }
          float rcp = 1.f / ((zz == 0.f) ? 1.f : zz);
          hlds[crow][h * 64 + cc]     = o0 * rcp;
          hlds[crow][h * 64 + cc + 1] = o1 * rcp; }
    }
    __syncthreads();

    int arow = b * 1024 + nbase + l15;
    float sfv[2][8];
    #pragma unroll
    for (int ks = 0; ks < 2; ++ks) {
        int fb = ks * 32 + l4 * 8;
        float4 m0a = *(const float4*)(&hlds[l15][fb]);
        float4 m0b = *(const float4*)(&hlds[l15][fb + 4]);
        float4 m1a = *(const float4*)(&hlds[l15][64 + fb]);
        float4 m1b = *(const float4*)(&hlds[l15][64 + fb + 4]);
        float4 m2a = *(const float4*)(&hlds[l15][128 + fb]);
        float4 m2b = *(const float4*)(&hlds[l15][128 + fb + 4]);
        const float* rp = rsum + (size_t)arow * 64 + fb;
        float4 r0 = *(const float4*)(rp);
        float4 r1 = *(const float4*)(rp + 4);
        float mv[8] = {m0a.x + m1a.x + m2a.x, m0a.y + m1a.y + m2a.y,
                       m0a.z + m1a.z + m2a.z, m0a.w + m1a.w + m2a.w,
                       m0b.x + m1b.x + m2b.x, m0b.y + m1b.y + m2b.y,
                       m0b.z + m1b.z + m2b.z, m0b.w + m1b.w + m2b.w};
        float rr[8] = {r0.x, r0.y, r0.z, r0.w, r1.x, r1.y, r1.z, r1.w};
        #pragma unroll
        for (int j = 0; j < 8; ++j) {
            float v = mv[j] * (1.f / 3.f);
            v = (v > 0.f) ? v : (fast_exp2(v * LOG2E) - 1.f);
            sfv[ks][j] = v + rr[j];
        }
    }

    if (w < 4) {
        bf16x8 ai[2], ah[2];
        #pragma unroll
        for (int ks = 0; ks < 2; ++ks) {
            union { unsigned u[4]; bf16x8 v; } ua, uh;
            int fb = ks * 32 + l4 * 8;
            float4 h0 = *(const float4*)(hprev + (size_t)arow * 64 + fb);
            float4 h1 = *(const float4*)(hprev + (size_t)arow * 64 + fb + 4);
            ua.u[0] = cvt_pk_bf16(sfv[ks][0], sfv[ks][1]);
            ua.u[1] = cvt_pk_bf16(sfv[ks][2], sfv[ks][3]);
            ua.u[2] = cvt_pk_bf16(sfv[ks][4], sfv[ks][5]);
            ua.u[3] = cvt_pk_bf16(sfv[ks][6], sfv[ks][7]);
            uh.u[0] = cvt_pk_bf16(h0.x, h0.y);
            uh.u[1] = cvt_pk_bf16(h0.z, h0.w);
            uh.u[2] = cvt_pk_bf16(h1.x, h1.y);
            uh.u[3] = cvt_pk_bf16(h1.z, h1.w);
            ai[ks] = ua.v; ah[ks] = uh.v;
        }
        f32x4 gi0 = (f32x4)0.f, gi1 = (f32x4)0.f, gi2 = (f32x4)0.f;
        f32x4 gh0 = (f32x4)0.f, gh1 = (f32x4)0.f, gh2 = (f32x4)0.f;
        #pragma unroll
        for (int ks = 0; ks < 2; ++ks) {
            int k = ks * 32 + l4 * 8;
            int n0 = (0 * 4 + w) * 16 + l15;
            int n1 = (1 * 4 + w) * 16 + l15;
            int n2 = (2 * 4 + w) * 16 + l15;
            gi0 = MFMA(ai[ks], *(const bf16x8*)(wi16 + (size_t)n0 * 64 + k), gi0, 0, 0, 0);
            gi1 = MFMA(ai[ks], *(const bf16x8*)(wi16 + (size_t)n1 * 64 + k), gi1, 0, 0, 0);
            gi2 = MFMA(ai[ks], *(const bf16x8*)(wi16 + (size_t)n2 * 64 + k), gi2, 0, 0, 0);
            gh0 = MFMA(ah[ks], *(const bf16x8*)(wh16 + (size_t)n0 * 64 + k), gh0, 0, 0, 0);
            gh1 = MFMA(ah[ks], *(const bf16x8*)(wh16 + (size_t)n1 * 64 + k), gh1, 0, 0, 0);
            gh2 = MFMA(ah[ks], *(const bf16x8*)(wh16 + (size_t)n2 * 64 + k), gh2, 0, 0, 0);
        }
        int hc = w * 16 + l15;
        float bir = bi[hc], biz = bi[64 + hc], bin = bi[128 + hc];
        float bhr = bh_[hc], bhz = bh_[64 + hc], bhn = bh_[128 + hc];
        #pragma unroll
        for (int r = 0; r < 4; ++r) {
            int rloc = l4 * 4 + r;
            int rowg = b * 1024 + nbase + rloc;
            float rrg = (gi0[r] + bir) + (gh0[r] + bhr);
            float zzg = (gi1[r] + biz) + (gh1[r] + bhz);
            float rg = 1.f / (1.f + fast_exp2(-rrg * LOG2E));
            float zg = 1.f / (1.f + fast_exp2(-zzg * LOG2E));
            float narg = (gi2[r] + bin) + rg * (gh2[r] + bhn);
            narg = fminf(fmaxf(narg, -15.f), 15.f);
            float e2 = fast_exp2(2.f * narg * LOG2E);
            float ng = (e2 - 1.f) / (e2 + 1.f);
            float hp = hprev[(size_t)rowg * 64 + hc];
            float hv = (1.f - zg) * ng + zg * hp;
            hnew[(size_t)rowg * 64 + hc] = hv;
            hnlds[rloc * 72 + hc] = f2bf(hv);
        }
    }
    __syncthreads();

    if (w == 4) {
        f32x4 c0 = (f32x4)0.f, c1 = (f32x4)0.f;
        #pragma unroll
        for (int ks = 0; ks < 2; ++ks) {
            int k = ks * 32 + l4 * 8;
            bf16x8 a = *(const bf16x8*)(&hnlds[l15 * 72 + k]);
            c0 = MFMA(a, *(const bf16x8*)(Wa1T + (size_t)(l15) * 64 + k), c0, 0, 0, 0);
            c1 = MFMA(a, *(const bf16x8*)(Wa1T + (size_t)(16 + l15) * 64 + k), c1, 0, 0, 0);
        }
        float p0[4] = {0.f, 0.f, 0.f, 0.f}, p1[4] = {0.f, 0.f, 0.f, 0.f};
        #pragma unroll
        for (int t = 0; t < 2; ++t) {
            int c = t * 16 + l15;
            float b1 = ba1[c], w20 = Wa2[c * 2], w21 = Wa2[c * 2 + 1];
            f32x4 av = t ? c1 : c0;
            #pragma unroll
            for (int r = 0; r < 4; ++r) {
                float v = fmaxf(av[r] + b1, 0.f);
                p0[r] += v * w20; p1[r] += v * w21;
            }
        }
        #pragma unroll
        for (int r = 0; r < 4; ++r) {
            #pragma unroll
            for (int off = 1; off < 16; off <<= 1) {
                p0[r] += __shfl_xor(p0[r], off);
                p1[r] += __shfl_xor(p1[r], off);
            }
            float l0 = p0[r] + ba2[0], l1 = p1[r] + ba2[1];
            float mm = fmaxf(l0, l1);
            float e0 = fast_exp2((l0 - mm) * LOG2E);
            float e1 = fast_exp2((l1 - mm) * LOG2E);
            float s = 1.f / (e0 + e1);
            if (l15 == 0) {
                int rowg = b * 1024 + nbase + 4 * l4 + r;
                probs[(size_t)rowg * 2]     = e0 * s;
                probs[(size_t)rowg * 2 + 1] = e1 * s;
            }
        }
    } else if (w == 5) {
        f32x4 c0 = (f32x4)0.f, c1 = (f32x4)0.f;
        #pragma unroll
        for (int ks = 0; ks < 2; ++ks) {
            int k = ks * 32 + l4 * 8;
            bf16x8 a = *(const bf16x8*)(&hnlds[l15 * 72 + k]);
            c0 = MFMA(a, *(const bf16x8*)(Wc1T + (size_t)(l15) * 64 + k), c0, 0, 0, 0);
            c1 = MFMA(a, *(const bf16x8*)(Wc1T + (size_t)(16 + l15) * 64 + k), c1, 0, 0, 0);
        }
        float pv[4] = {0.f, 0.f, 0.f, 0.f};
        #pragma unroll
        for (int t = 0; t < 2; ++t) {
            int c = t * 16 + l15;
            float b1 = bc1[c], w2 = Wc2[c];
            f32x4 av = t ? c1 : c0;
            #pragma unroll
            for (int r = 0; r < 4; ++r) {
                float v = fmaxf(av[r] + b1, 0.f);
                pv[r] += v * w2;
            }
        }
        #pragma unroll
        for (int r = 0; r < 4; ++r) {
            #pragma unroll
            for (int off = 1; off < 16; off <<= 1) pv[r] += __shfl_xor(pv[r], off);
            if (l15 == 0) {
                int rowg = b * 1024 + nbase + 4 * l4 + r;
                value[rowg] = pv[r] + bc2[0];
            }
        }
    }
}

// ---------------------------------------------------------------------------
extern "C" void kernel_launch(void* const* d_in, const int* in_sizes, int n_in,
                              void* d_out, int out_size, void* d_ws, size_t ws_size,
                              hipStream_t stream)
{
    const float* x      = (const float*)d_in[0];
    const int*   adj    = (const int*)d_in[1];
    const float* h_prev = (const float*)d_in[2];
    const float* W0  = (const float*)d_in[3];
    const float* as0 = (const float*)d_in[4];
    const float* ad0 = (const float*)d_in[5];
    const float* W1  = (const float*)d_in[6];
    const float* as1 = (const float*)d_in[7];
    const float* ad1 = (const float*)d_in[8];
    const float* W2  = (const float*)d_in[9];
    const float* as2 = (const float*)d_in[10];
    const float* ad2 = (const float*)d_in[11];
    const float* gwi = (const float*)d_in[12];
    const float* gwh = (const float*)d_in[13];
    const float* gbi = (const float*)d_in[14];
    const float* gbh = (const float*)d_in[15];
    const float* Wa1 = (const float*)d_in[16];
    const float* ba1 = (const float*)d_in[17];
    const float* Wa2 = (const float*)d_in[18];
    const float* ba2 = (const float*)d_in[19];
    const float* Wc1 = (const float*)d_in[20];
    const float* bc1 = (const float*)d_in[21];
    const float* Wc2 = (const float*)d_in[22];
    const float* bc2 = (const float*)d_in[23];

    float* out   = (float*)d_out;
    float* probs = out;            // (8,1024,2)
    float* value = out + 16384;    // (8,1024,1)
    float* hnew  = out + 24576;    // (8,1024,64)

    char* p = (char*)d_ws;
    auto alloc = [&](size_t bytes) { char* q = p; p += (bytes + 255) & ~(size_t)255; return q; };
    auto*  maskb = (unsigned long long*)alloc(16384 * 8);
    auto*  xpad  = (unsigned short*)alloc((size_t)NROWS * 32 * 2);
    auto*  hp16  = (unsigned short*)alloc((size_t)NROWS * 64 * 2);
    auto*  VT_A  = (unsigned short*)alloc((size_t)8 * 3 * 64 * 1024 * 2);
    auto*  VT_B  = (unsigned short*)alloc((size_t)8 * 3 * 64 * 1024 * 2);
    float* stA   = (float*)alloc((size_t)24576 * 4);
    float* dtA   = (float*)alloc((size_t)24576 * 4);
    float* stB   = (float*)alloc((size_t)24576 * 4);
    float* dtB   = (float*)alloc((size_t)24576 * 4);
    float* rsum  = (float*)alloc((size_t)NROWS * 64 * 4);
    auto*  W0Tp  = (unsigned short*)alloc(192 * 32 * 2);
    auto*  W1T   = (unsigned short*)alloc(192 * 64 * 2);
    auto*  W2T   = (unsigned short*)alloc(192 * 64 * 2);
    auto*  wi16  = (unsigned short*)alloc(192 * 64 * 2);
    auto*  wh16  = (unsigned short*)alloc(192 * 64 * 2);
    auto*  Wa1T  = (unsigned short*)alloc(32 * 64 * 2);
    auto*  Wc1T  = (unsigned short*)alloc(32 * 64 * 2);
    auto*  Wsd0  = (unsigned short*)alloc(16 * 32 * 2);
    auto*  Wsd1  = (unsigned short*)alloc(16 * 64 * 2);
    auto*  Wsd2  = (unsigned short*)alloc(16 * 64 * 2);
    (void)ws_size; (void)in_sizes; (void)n_in; (void)out_size;

    const unsigned int* maskw = (const unsigned int*)maskb;

    // VERIFIED round-5 front end
    setup_kernel<<<1024, 256, 0, stream>>>(
        x, adj, h_prev, W0, as0, ad0, W1, as1, ad1, W2, as2, ad2,
        gwi, gwh, Wa1, Wc1,
        maskb, xpad, hp16, W0Tp, W1T, W2T, wi16, wh16, Wa1T, Wc1T,
        Wsd0, Wsd1, Wsd2);
    proj_kernel<32, 0><<<512, 256, 0, stream>>>(xpad, nullptr, nullptr, W0Tp, Wsd0, VT_A, stA, dtA);

    // Fusion back end under test
    fused_kernel<1><<<512, 512, 0, stream>>>(
        VT_A, stA, dtA, maskw, W1T, Wsd1, rsum, VT_B, stB, dtB);
    fused_kernel<2><<<512, 512, 0, stream>>>(
        VT_B, stB, dtB, maskw, W2T, Wsd2, rsum, VT_A, stA, dtA);
    f2g_kernel<<<512, 512, 0, stream>>>(
        VT_A, stA, dtA, maskw, rsum, h_prev, wi16, wh16, gbi, gbh,
        Wa1T, Wc1T, ba1, Wa2, ba2, bc1, Wc2, bc2, hnew, probs, value);
}

// Round 10
// 84.443 us; speedup vs baseline: 1.2398x; 1.2398x over previous
//
#include <hip/hip_runtime.h>
#include <hip/hip_bf16.h>
#include <stdint.h>

#define LOG2E 1.44269504f
#define NROWS 8192

using bf16x8 = __attribute__((ext_vector_type(8))) short;
using f32x4  = __attribute__((ext_vector_type(4))) float;

__device__ __forceinline__ unsigned short f2bf(float f) {
    unsigned u = __float_as_uint(f);
    u += 0x7fff + ((u >> 16) & 1);          // RNE
    return (unsigned short)(u >> 16);
}
__device__ __forceinline__ unsigned cvt_pk_bf16(float lo, float hi) {
    unsigned r;
    asm("v_cvt_pk_bf16_f32 %0, %1, %2" : "=v"(r) : "v"(lo), "v"(hi));
    return r;
}
__device__ __forceinline__ float fast_exp2(float x) { return __builtin_amdgcn_exp2f(x); }

#define MFMA __builtin_amdgcn_mfma_f32_16x16x32_bf16

// ---------------------------------------------------------------------------
// Setup (round-5 verbatim, VERIFIED). Grid 1024 x 256.
// ---------------------------------------------------------------------------
__global__ __launch_bounds__(256) void setup_kernel(
    const float* __restrict__ x, const int* __restrict__ adj, const float* __restrict__ h_prev,
    const float* __restrict__ W0, const float* __restrict__ as0, const float* __restrict__ ad0,
    const float* __restrict__ W1, const float* __restrict__ as1, const float* __restrict__ ad1,
    const float* __restrict__ W2, const float* __restrict__ as2, const float* __restrict__ ad2,
    const float* __restrict__ gwi, const float* __restrict__ gwh,
    const float* __restrict__ Wa1, const float* __restrict__ Wc1,
    unsigned long long* __restrict__ maskbits, unsigned short* __restrict__ xpad,
    unsigned short* __restrict__ hp16,
    unsigned short* __restrict__ W0Tp, unsigned short* __restrict__ W1T, unsigned short* __restrict__ W2T,
    unsigned short* __restrict__ wi16, unsigned short* __restrict__ wh16,
    unsigned short* __restrict__ Wa1T, unsigned short* __restrict__ Wc1T,
    unsigned short* __restrict__ Wsd0, unsigned short* __restrict__ Wsd1, unsigned short* __restrict__ Wsd2)
{
    int tid  = blockIdx.x * 256 + threadIdx.x;   // 0 .. 262143
    int lane = threadIdx.x & 63;
    int wv   = tid >> 6;

    #pragma unroll
    for (int i = 0; i < 4; ++i) {
        int w   = wv * 4 + i;
        int row = w >> 4, wc = w & 15;
        int j   = wc * 64 + lane;
        unsigned long long m = __ballot(adj[row * 1024 + j] > 0);
        if (lane == 0) maskbits[w] = m;
    }
    {
        int n = tid >> 5, k = tid & 31;
        xpad[tid] = (k < 3) ? f2bf(x[n * 3 + k]) : (unsigned short)0;
    }
    hp16[tid]          = f2bf(h_prev[tid]);
    hp16[tid + 262144] = f2bf(h_prev[tid + 262144]);
    if (tid < 12288) {
        int n = tid >> 6, k = tid & 63;
        W1T[tid]  = f2bf(W1[k * 192 + n]);
        W2T[tid]  = f2bf(W2[k * 192 + n]);
        wi16[tid] = f2bf(gwi[tid]);
        wh16[tid] = f2bf(gwh[tid]);
    }
    if (tid < 6144) {
        int n = tid >> 5, k = tid & 31;
        W0Tp[tid] = (k < 3) ? f2bf(W0[k * 192 + n]) : (unsigned short)0;
    }
    if (tid < 2048) {
        int n = tid >> 6, k = tid & 63;
        Wa1T[tid] = f2bf(Wa1[k * 32 + n]);
        Wc1T[tid] = f2bf(Wc1[k * 32 + n]);
    }
    if (tid < 16 * 32) {
        int c = tid >> 5, k = tid & 31;
        float v = 0.f;
        if (c < 6 && k < 3) {
            int h = c >> 1; const float* a = (c & 1) ? ad0 : as0;
            for (int f = 0; f < 64; ++f) v += W0[k * 192 + h * 64 + f] * a[h * 64 + f];
        }
        Wsd0[tid] = f2bf(v);
    }
    if (tid < 16 * 64) {
        int c = tid >> 6, k = tid & 63;
        float v1 = 0.f, v2 = 0.f;
        if (c < 6) {
            int h = c >> 1;
            const float* a1 = (c & 1) ? ad1 : as1;
            const float* a2 = (c & 1) ? ad2 : as2;
            for (int f = 0; f < 64; ++f) {
                v1 += W1[k * 192 + h * 64 + f] * a1[h * 64 + f];
                v2 += W2[k * 192 + h * 64 + f] * a2[h * 64 + f];
            }
        }
        Wsd1[tid] = f2bf(v1);
        Wsd2[tid] = f2bf(v2);
    }
}

// ---------------------------------------------------------------------------
// Projection (round-5 verbatim, VERIFIED). Grid 512 x 256, XCD-swizzled.
// ---------------------------------------------------------------------------
template<int KDIM, int MODE>
__global__ __launch_bounds__(256) void proj_kernel(
    const unsigned short* __restrict__ A16,
    const float* __restrict__ haccp,          // [b][1024][192]
    float* __restrict__ rsum,                 // [8192][64]
    const unsigned short* __restrict__ WT,    // [192][KDIM]
    const unsigned short* __restrict__ WsdT,  // [16][KDIM]
    unsigned short* __restrict__ VT,
    float* __restrict__ st, float* __restrict__ dt)
{
    int b     = blockIdx.x & 7;
    int nbase = (int)(blockIdx.x >> 3) << 4;
    int fg = threadIdx.x >> 6, l = threadIdx.x & 63;
    int l15 = l & 15, l4 = l >> 4;
    int row = b * 1024 + nbase + l15;
    constexpr int NK = KDIM / 32;

    bf16x8 afr[NK];
    if constexpr (MODE == 0) {
        #pragma unroll
        for (int ks = 0; ks < NK; ++ks)
            afr[ks] = *(const bf16x8*)(A16 + (size_t)row * KDIM + ks * 32 + l4 * 8);
    } else {
        float sf[2][8];
        #pragma unroll
        for (int ks = 0; ks < 2; ++ks) {
            int fb = ks * 32 + l4 * 8;
            const float* hp = haccp + (size_t)row * 192 + fb;
            float4 a0 = *(const float4*)(hp);       float4 a1 = *(const float4*)(hp + 4);
            float4 c0 = *(const float4*)(hp + 64);  float4 c1 = *(const float4*)(hp + 68);
            float4 e0 = *(const float4*)(hp + 128); float4 e1 = *(const float4*)(hp + 132);
            float m[8] = {a0.x + c0.x + e0.x, a0.y + c0.y + e0.y, a0.z + c0.z + e0.z, a0.w + c0.w + e0.w,
                          a1.x + c1.x + e1.x, a1.y + c1.y + e1.y, a1.z + c1.z + e1.z, a1.w + c1.w + e1.w};
            float r[8] = {0.f,0.f,0.f,0.f,0.f,0.f,0.f,0.f};
            if constexpr (MODE == 2) {
                const float* rp = rsum + (size_t)row * 64 + fb;
                float4 r0 = *(const float4*)(rp); float4 r1 = *(const float4*)(rp + 4);
                r[0]=r0.x; r[1]=r0.y; r[2]=r0.z; r[3]=r0.w;
                r[4]=r1.x; r[5]=r1.y; r[6]=r1.z; r[7]=r1.w;
            }
            #pragma unroll
            for (int j = 0; j < 8; ++j) {
                float v = m[j] * (1.f / 3.f);
                v = (v > 0.f) ? v : (fast_exp2(v * LOG2E) - 1.f);
                sf[ks][j] = v + r[j];
            }
        }
        __syncthreads();
        if (fg == 0) {
            #pragma unroll
            for (int ks = 0; ks < 2; ++ks) {
                float* rp = rsum + (size_t)row * 64 + ks * 32 + l4 * 8;
                *(float4*)(rp)     = make_float4(sf[ks][0], sf[ks][1], sf[ks][2], sf[ks][3]);
                *(float4*)(rp + 4) = make_float4(sf[ks][4], sf[ks][5], sf[ks][6], sf[ks][7]);
            }
        }
        #pragma unroll
        for (int ks = 0; ks < 2; ++ks) {
            union { unsigned u[4]; bf16x8 v; } uu;
            #pragma unroll
            for (int jj = 0; jj < 4; ++jj)
                uu.u[jj] = cvt_pk_bf16(sf[ks][2 * jj], sf[ks][2 * jj + 1]);
            afr[ks] = uu.v;
        }
    }

    f32x4 acc[3] = {(f32x4)0.f, (f32x4)0.f, (f32x4)0.f};
    f32x4 sdacc  = (f32x4)0.f;
    #pragma unroll
    for (int ks = 0; ks < NK; ++ks) {
        int k = ks * 32 + l4 * 8;
        #pragma unroll
        for (int t = 0; t < 3; ++t) {
            int n = (fg * 3 + t) * 16 + l15;
            bf16x8 bf = *(const bf16x8*)(WT + (size_t)n * KDIM + k);
            acc[t] = MFMA(afr[ks], bf, acc[t], 0, 0, 0);
        }
        if (fg == 0) {
            bf16x8 bsd = *(const bf16x8*)(WsdT + (size_t)l15 * KDIM + k);
            sdacc = MFMA(afr[ks], bsd, sdacc, 0, 0, 0);
        }
    }
    #pragma unroll
    for (int t = 0; t < 3; ++t) {
        int hf = (fg * 3 + t) * 16 + l15;
        size_t base = ((size_t)(b * 3 + (hf >> 6)) * 64 + (hf & 63)) * 1024 + nbase + l4 * 4;
        uint2 pk;
        pk.x = cvt_pk_bf16(acc[t][0], acc[t][1]);
        pk.y = cvt_pk_bf16(acc[t][2], acc[t][3]);
        *(uint2*)(VT + base) = pk;
    }
    if (fg == 0 && l15 < 6) {
        int h = l15 >> 1;
        float* dst = (l15 & 1) ? dt : st;
        size_t base = (size_t)(b * 3 + h) * 1024 + nbase + l4 * 4;
        #pragma unroll
        for (int r = 0; r < 4; ++r) dst[base + r] = sdacc[r];
    }
}

// ---------------------------------------------------------------------------
// Attention (round-5 math, NEW 3-deep rotating load pipeline).
// Grid 768 XCD-swizzled; block 256 = 4 waves; wave w covers 256 j (8 iters).
// Factored softmax: p = mask * max(F1_j, R_i*F2_j). Compute order identical
// to round 5 (it ascending) -> bit-identical output.
// ---------------------------------------------------------------------------
__global__ __launch_bounds__(256) void attn_head_kernel(
    const unsigned short* __restrict__ VT,
    const float* __restrict__ st, const float* __restrict__ dt,
    const unsigned int* __restrict__ maskw,   // [1024 rows][32 words]
    float* __restrict__ hacc)                 // [b][1024][192]
{
    __shared__ float F1lds[1024];
    __shared__ float F2lds[1024];
    __shared__ unsigned int lmask[32 * 33];
    __shared__ float pO[4][32 * 68];
    __shared__ float pZ[4][32];

    int b     = blockIdx.x & 7;               // = XCD
    int q     = blockIdx.x >> 3;              // 0..95
    int h     = q >> 5;
    int bh    = b * 3 + h;
    int ibase = (q & 31) << 5;
    int w = threadIdx.x >> 6, l = threadIdx.x & 63;
    int l15 = l & 15, l4 = l >> 4;

    #pragma unroll
    for (int i = 0; i < 4; ++i) {
        int idx = threadIdx.x + i * 256;
        int row = idx >> 5, wd = idx & 31;
        lmask[row * 33 + wd] = maskw[(size_t)(ibase + row) * 32 + wd];
    }
    {
        int t4 = threadIdx.x * 4;
        float4 dv4 = *(const float4*)(dt + (size_t)bh * 1024 + t4);
        *(float4*)(F1lds + t4) = make_float4(
            fast_exp2(dv4.x * LOG2E), fast_exp2(dv4.y * LOG2E),
            fast_exp2(dv4.z * LOG2E), fast_exp2(dv4.w * LOG2E));
        *(float4*)(F2lds + t4) = make_float4(
            fast_exp2(dv4.x * (0.2f * LOG2E)), fast_exp2(dv4.y * (0.2f * LOG2E)),
            fast_exp2(dv4.z * (0.2f * LOG2E)), fast_exp2(dv4.w * (0.2f * LOG2E)));
    }
    __syncthreads();

    float R0 = fast_exp2(st[(size_t)bh * 1024 + ibase + l15]      * (-0.8f * LOG2E));
    float R1 = fast_exp2(st[(size_t)bh * 1024 + ibase + 16 + l15] * (-0.8f * LOG2E));
    const unsigned short* vbase = VT + (size_t)bh * 64 * 1024;

    f32x4 acc[2][4];
    #pragma unroll
    for (int rg = 0; rg < 2; ++rg)
        #pragma unroll
        for (int f4 = 0; f4 < 4; ++f4) acc[rg][f4] = (f32x4)0.f;
    float z0 = 0.f, z1 = 0.f;
    int jb = w * 256;
    int w8 = w * 8;

    // 3-deep rotating pipeline; all slot indices become compile-time
    // constants after full unroll (no scratch).
    float4 F1A[3], F1B[3], F2A[3], F2B[3];
    bf16x8 VA[3], VB[3], VC[3], VD[3];

    auto LDF = [&](int it) {
        int s = it % 3;
        int kk = jb + it * 32 + l4 * 8;
        F1A[s] = *(const float4*)(F1lds + kk);
        F1B[s] = *(const float4*)(F1lds + kk + 4);
        F2A[s] = *(const float4*)(F2lds + kk);
        F2B[s] = *(const float4*)(F2lds + kk + 4);
    };
    auto LDV = [&](int it) {
        int s = it % 3;
        int kk = jb + it * 32 + l4 * 8;
        VA[s] = *(const bf16x8*)(vbase + (size_t)(l15)      * 1024 + kk);
        VB[s] = *(const bf16x8*)(vbase + (size_t)(16 + l15) * 1024 + kk);
        VC[s] = *(const bf16x8*)(vbase + (size_t)(32 + l15) * 1024 + kk);
        VD[s] = *(const bf16x8*)(vbase + (size_t)(48 + l15) * 1024 + kk);
    };

    LDV(0); LDV(1); LDV(2);
    LDF(0); LDF(1); LDF(2);

    #pragma unroll
    for (int it = 0; it < 8; ++it) {
        int s = it % 3;
        unsigned m0 = (lmask[l15 * 33 + w8 + it]        >> (l4 * 8)) & 0xffu;
        unsigned m1 = (lmask[(16 + l15) * 33 + w8 + it] >> (l4 * 8)) & 0xffu;
        float f1[8] = {F1A[s].x, F1A[s].y, F1A[s].z, F1A[s].w,
                       F1B[s].x, F1B[s].y, F1B[s].z, F1B[s].w};
        float f2[8] = {F2A[s].x, F2A[s].y, F2A[s].z, F2A[s].w,
                       F2B[s].x, F2B[s].y, F2B[s].z, F2B[s].w};
        bf16x8 Va = VA[s], Vb = VB[s], Vc = VC[s], Vd = VD[s];

        float p0[8], p1[8];
        #pragma unroll
        for (int j = 0; j < 8; ++j) {
            float a0 = fmaxf(f1[j], R0 * f2[j]);
            p0[j] = ((m0 >> j) & 1) ? a0 : 0.f;
            z0 += p0[j];
            float a1 = fmaxf(f1[j], R1 * f2[j]);
            p1[j] = ((m1 >> j) & 1) ? a1 : 0.f;
            z1 += p1[j];
        }
        union { unsigned u[4]; bf16x8 v; } ua, ub;
        #pragma unroll
        for (int jj = 0; jj < 4; ++jj) {
            ua.u[jj] = cvt_pk_bf16(p0[2 * jj], p0[2 * jj + 1]);
            ub.u[jj] = cvt_pk_bf16(p1[2 * jj], p1[2 * jj + 1]);
        }
        // refill slot s for iteration it+3 (current values already consumed)
        if (it + 3 < 8) { LDV(it + 3); LDF(it + 3); }

        acc[0][0] = MFMA(ua.v, Va, acc[0][0], 0, 0, 0);
        acc[0][1] = MFMA(ua.v, Vb, acc[0][1], 0, 0, 0);
        acc[0][2] = MFMA(ua.v, Vc, acc[0][2], 0, 0, 0);
        acc[0][3] = MFMA(ua.v, Vd, acc[0][3], 0, 0, 0);
        acc[1][0] = MFMA(ub.v, Va, acc[1][0], 0, 0, 0);
        acc[1][1] = MFMA(ub.v, Vb, acc[1][1], 0, 0, 0);
        acc[1][2] = MFMA(ub.v, Vc, acc[1][2], 0, 0, 0);
        acc[1][3] = MFMA(ub.v, Vd, acc[1][3], 0, 0, 0);
    }

    z0 += __shfl_xor(z0, 16); z0 += __shfl_xor(z0, 32);
    z1 += __shfl_xor(z1, 16); z1 += __shfl_xor(z1, 32);
    if (l4 == 0) pZ[w][l15] = z0;
    if (l4 == 1) pZ[w][16 + l15] = z1;
    #pragma unroll
    for (int rg = 0; rg < 2; ++rg)
        #pragma unroll
        for (int f4 = 0; f4 < 4; ++f4)
            #pragma unroll
            for (int r = 0; r < 4; ++r)
                pO[w][(rg * 16 + l4 * 4 + r) * 68 + f4 * 16 + l15] = acc[rg][f4][r];
    __syncthreads();

    int row = threadIdx.x >> 3;
    int fo  = (threadIdx.x & 7) * 8;
    float zs = pZ[0][row] + pZ[1][row] + pZ[2][row] + pZ[3][row];
    float rcp = 1.f / ((zs == 0.f) ? 1.f : zs);
    float o[8] = {0.f,0.f,0.f,0.f,0.f,0.f,0.f,0.f};
    #pragma unroll
    for (int ww = 0; ww < 4; ++ww) {
        const float* pp = &pO[ww][row * 68 + fo];
        float4 a = *(const float4*)(pp);
        float4 c = *(const float4*)(pp + 4);
        o[0] += a.x; o[1] += a.y; o[2] += a.z; o[3] += a.w;
        o[4] += c.x; o[5] += c.y; o[6] += c.z; o[7] += c.w;
    }
    float* op = hacc + (size_t)(b * 1024 + ibase + row) * 192 + h * 64 + fo;
    *(float4*)(op)     = make_float4(o[0] * rcp, o[1] * rcp, o[2] * rcp, o[3] * rcp);
    *(float4*)(op + 4) = make_float4(o[4] * rcp, o[5] * rcp, o[6] * rcp, o[7] * rcp);
}

// ---------------------------------------------------------------------------
// GRU + heads fused (round-5 verbatim, VERIFIED). Grid 256, XCD-swizzled.
// ---------------------------------------------------------------------------
__global__ __launch_bounds__(256) void gruheads_kernel(
    const float* __restrict__ haccp, const float* __restrict__ rsum,
    const unsigned short* __restrict__ hp16,
    const unsigned short* __restrict__ wi16, const unsigned short* __restrict__ wh16,
    const float* __restrict__ bi, const float* __restrict__ bh,
    const float* __restrict__ hprev,
    const unsigned short* __restrict__ Wa1T, const unsigned short* __restrict__ Wc1T,
    const float* __restrict__ ba1, const float* __restrict__ Wa2, const float* __restrict__ ba2,
    const float* __restrict__ bc1, const float* __restrict__ Wc2, const float* __restrict__ bc2,
    float* __restrict__ hnew, float* __restrict__ probs, float* __restrict__ value)
{
    __shared__ unsigned short hnlds[32 * 72];

    int b     = blockIdx.x & 7;
    int nbase = (int)(blockIdx.x >> 3) << 5;
    int w = threadIdx.x >> 6, l = threadIdx.x & 63;
    int rh = w & 1, g = w >> 1;
    int l15 = l & 15, l4 = l >> 4;
    int rowbase = b * 1024 + nbase + rh * 16;
    int arow = rowbase + l15;

    bf16x8 ai[2];
    #pragma unroll
    for (int ks = 0; ks < 2; ++ks) {
        int fb = ks * 32 + l4 * 8;
        const float* hp = haccp + (size_t)arow * 192 + fb;
        float4 a0 = *(const float4*)(hp);       float4 a1 = *(const float4*)(hp + 4);
        float4 c0 = *(const float4*)(hp + 64);  float4 c1 = *(const float4*)(hp + 68);
        float4 e0 = *(const float4*)(hp + 128); float4 e1 = *(const float4*)(hp + 132);
        const float* rp = rsum + (size_t)arow * 64 + fb;
        float4 r0 = *(const float4*)(rp);       float4 r1 = *(const float4*)(rp + 4);
        float m[8] = {a0.x + c0.x + e0.x, a0.y + c0.y + e0.y, a0.z + c0.z + e0.z, a0.w + c0.w + e0.w,
                      a1.x + c1.x + e1.x, a1.y + c1.y + e1.y, a1.z + c1.z + e1.z, a1.w + c1.w + e1.w};
        float rr[8] = {r0.x, r0.y, r0.z, r0.w, r1.x, r1.y, r1.z, r1.w};
        float sf[8];
        #pragma unroll
        for (int j = 0; j < 8; ++j) {
            float v = m[j] * (1.f / 3.f);
            v = (v > 0.f) ? v : (fast_exp2(v * LOG2E) - 1.f);
            sf[j] = v + rr[j];
        }
        union { unsigned u[4]; bf16x8 v; } uu;
        #pragma unroll
        for (int jj = 0; jj < 4; ++jj)
            uu.u[jj] = cvt_pk_bf16(sf[2 * jj], sf[2 * jj + 1]);
        ai[ks] = uu.v;
    }

    f32x4 gi[2][3], gh[2][3];
    #pragma unroll
    for (int t = 0; t < 2; ++t)
        #pragma unroll
        for (int q = 0; q < 3; ++q) { gi[t][q] = (f32x4)0.f; gh[t][q] = (f32x4)0.f; }

    #pragma unroll
    for (int ks = 0; ks < 2; ++ks) {
        int k = ks * 32 + l4 * 8;
        bf16x8 ah = *(const bf16x8*)(hp16 + (size_t)arow * 64 + k);
        #pragma unroll
        for (int t = 0; t < 2; ++t) {
            #pragma unroll
            for (int q = 0; q < 3; ++q) {
                int n = (q * 4 + g * 2 + t) * 16 + l15;
                bf16x8 bwi = *(const bf16x8*)(wi16 + (size_t)n * 64 + k);
                bf16x8 bwh = *(const bf16x8*)(wh16 + (size_t)n * 64 + k);
                gi[t][q] = MFMA(ai[ks], bwi, gi[t][q], 0, 0, 0);
                gh[t][q] = MFMA(ah,     bwh, gh[t][q], 0, 0, 0);
            }
        }
    }
    #pragma unroll
    for (int t = 0; t < 2; ++t) {
        int c = (g * 2 + t) * 16 + l15;
        float bir = bi[c], biz = bi[64 + c], bin = bi[128 + c];
        float bhr = bh[c], bhz = bh[64 + c], bhn = bh[128 + c];
        #pragma unroll
        for (int r = 0; r < 4; ++r) {
            int rloc = rh * 16 + 4 * l4 + r;
            int row = b * 1024 + nbase + rloc;
            float rr = (gi[t][0][r] + bir) + (gh[t][0][r] + bhr);
            float zz = (gi[t][1][r] + biz) + (gh[t][1][r] + bhz);
            float rg = 1.f / (1.f + fast_exp2(-rr * LOG2E));
            float zg = 1.f / (1.f + fast_exp2(-zz * LOG2E));
            float narg = (gi[t][2][r] + bin) + rg * (gh[t][2][r] + bhn);
            narg = fminf(fmaxf(narg, -15.f), 15.f);
            float e2 = fast_exp2(2.f * narg * LOG2E);
            float ng = (e2 - 1.f) / (e2 + 1.f);
            float hp = hprev[(size_t)row * 64 + c];
            float hv = (1.f - zg) * ng + zg * hp;
            hnew[(size_t)row * 64 + c] = hv;
            hnlds[rloc * 72 + c] = f2bf(hv);
        }
    }
    __syncthreads();

    const unsigned short* WT = g ? Wc1T : Wa1T;
    f32x4 acc[2] = {(f32x4)0.f, (f32x4)0.f};
    #pragma unroll
    for (int ks = 0; ks < 2; ++ks) {
        int k = ks * 32 + l4 * 8;
        bf16x8 a = *(const bf16x8*)(&hnlds[(rh * 16 + l15) * 72 + k]);
        #pragma unroll
        for (int t = 0; t < 2; ++t) {
            bf16x8 bf = *(const bf16x8*)(WT + (size_t)(t * 16 + l15) * 64 + k);
            acc[t] = MFMA(a, bf, acc[t], 0, 0, 0);
        }
    }
    int rowbase2 = b * 1024 + nbase + rh * 16;
    if (g == 0) {
        float p0[4] = {0.f,0.f,0.f,0.f}, p1[4] = {0.f,0.f,0.f,0.f};
        #pragma unroll
        for (int t = 0; t < 2; ++t) {
            int c = t * 16 + l15;
            float b1 = ba1[c], w20 = Wa2[c * 2], w21 = Wa2[c * 2 + 1];
            #pragma unroll
            for (int r = 0; r < 4; ++r) {
                float v = fmaxf(acc[t][r] + b1, 0.f);
                p0[r] += v * w20; p1[r] += v * w21;
            }
        }
        #pragma unroll
        for (int r = 0; r < 4; ++r) {
            #pragma unroll
            for (int off = 1; off < 16; off <<= 1) {
                p0[r] += __shfl_xor(p0[r], off);
                p1[r] += __shfl_xor(p1[r], off);
            }
            float l0 = p0[r] + ba2[0], l1 = p1[r] + ba2[1];
            float mm = fmaxf(l0, l1);
            float e0 = fast_exp2((l0 - mm) * LOG2E);
            float e1 = fast_exp2((l1 - mm) * LOG2E);
            float s = 1.f / (e0 + e1);
            if (l15 == 0) {
                int row = rowbase2 + 4 * l4 + r;
                probs[(size_t)row * 2]     = e0 * s;
                probs[(size_t)row * 2 + 1] = e1 * s;
            }
        }
    } else {
        float pv[4] = {0.f,0.f,0.f,0.f};
        #pragma unroll
        for (int t = 0; t < 2; ++t) {
            int c = t * 16 + l15;
            float b1 = bc1[c], w2 = Wc2[c];
            #pragma unroll
            for (int r = 0; r < 4; ++r) {
                float v = fmaxf(acc[t][r] + b1, 0.f);
                pv[r] += v * w2;
            }
        }
        #pragma unroll
        for (int r = 0; r < 4; ++r) {
            #pragma unroll
            for (int off = 1; off < 16; off <<= 1) pv[r] += __shfl_xor(pv[r], off);
            if (l15 == 0) {
                int row = rowbase2 + 4 * l4 + r;
                value[row] = pv[r] + bc2[0];
            }
        }
    }
}

// ---------------------------------------------------------------------------
extern "C" void kernel_launch(void* const* d_in, const int* in_sizes, int n_in,
                              void* d_out, int out_size, void* d_ws, size_t ws_size,
                              hipStream_t stream)
{
    const float* x      = (const float*)d_in[0];
    const int*   adj    = (const int*)d_in[1];
    const float* h_prev = (const float*)d_in[2];
    const float* W0  = (const float*)d_in[3];
    const float* as0 = (const float*)d_in[4];
    const float* ad0 = (const float*)d_in[5];
    const float* W1  = (const float*)d_in[6];
    const float* as1 = (const float*)d_in[7];
    const float* ad1 = (const float*)d_in[8];
    const float* W2  = (const float*)d_in[9];
    const float* as2 = (const float*)d_in[10];
    const float* ad2 = (const float*)d_in[11];
    const float* gwi = (const float*)d_in[12];
    const float* gwh = (const float*)d_in[13];
    const float* gbi = (const float*)d_in[14];
    const float* gbh = (const float*)d_in[15];
    const float* Wa1 = (const float*)d_in[16];
    const float* ba1 = (const float*)d_in[17];
    const float* Wa2 = (const float*)d_in[18];
    const float* ba2 = (const float*)d_in[19];
    const float* Wc1 = (const float*)d_in[20];
    const float* bc1 = (const float*)d_in[21];
    const float* Wc2 = (const float*)d_in[22];
    const float* bc2 = (const float*)d_in[23];

    float* out   = (float*)d_out;
    float* probs = out;            // (8,1024,2)
    float* value = out + 16384;    // (8,1024,1)
    float* hnew  = out + 24576;    // (8,1024,64)

    char* p = (char*)d_ws;
    auto alloc = [&](size_t bytes) { char* q = p; p += (bytes + 255) & ~(size_t)255; return q; };
    auto* maskb = (unsigned long long*)alloc(16384 * 8);
    auto*  xpad  = (unsigned short*)alloc((size_t)NROWS * 32 * 2);
    auto*  hp16  = (unsigned short*)alloc((size_t)NROWS * 64 * 2);
    auto*  VT    = (unsigned short*)alloc((size_t)8 * 3 * 64 * 1024 * 2);
    float* st    = (float*)alloc((size_t)24576 * 4);
    float* dt    = (float*)alloc((size_t)24576 * 4);
    float* hacc  = (float*)alloc((size_t)8 * 1024 * 192 * 4);
    float* rsum  = (float*)alloc((size_t)NROWS * 64 * 4);
    auto*  W0Tp  = (unsigned short*)alloc(192 * 32 * 2);
    auto*  W1T   = (unsigned short*)alloc(192 * 64 * 2);
    auto*  W2T   = (unsigned short*)alloc(192 * 64 * 2);
    auto*  wi16  = (unsigned short*)alloc(192 * 64 * 2);
    auto*  wh16  = (unsigned short*)alloc(192 * 64 * 2);
    auto*  Wa1T  = (unsigned short*)alloc(32 * 64 * 2);
    auto*  Wc1T  = (unsigned short*)alloc(32 * 64 * 2);
    auto*  Wsd0  = (unsigned short*)alloc(16 * 32 * 2);
    auto*  Wsd1  = (unsigned short*)alloc(16 * 64 * 2);
    auto*  Wsd2  = (unsigned short*)alloc(16 * 64 * 2);
    (void)ws_size; (void)in_sizes; (void)n_in; (void)out_size;

    const unsigned int* maskw = (const unsigned int*)maskb;

    setup_kernel<<<1024, 256, 0, stream>>>(
        x, adj, h_prev, W0, as0, ad0, W1, as1, ad1, W2, as2, ad2,
        gwi, gwh, Wa1, Wc1,
        maskb, xpad, hp16, W0Tp, W1T, W2T, wi16, wh16, Wa1T, Wc1T,
        Wsd0, Wsd1, Wsd2);

    // Layer 0
    proj_kernel<32, 0><<<512, 256, 0, stream>>>(xpad, nullptr, nullptr, W0Tp, Wsd0, VT, st, dt);
    attn_head_kernel<<<768, 256, 0, stream>>>(VT, st, dt, maskw, hacc);
    // Layer 1
    proj_kernel<64, 1><<<512, 256, 0, stream>>>(nullptr, hacc, rsum, W1T, Wsd1, VT, st, dt);
    attn_head_kernel<<<768, 256, 0, stream>>>(VT, st, dt, maskw, hacc);
    // Layer 2
    proj_kernel<64, 2><<<512, 256, 0, stream>>>(nullptr, hacc, rsum, W2T, Wsd2, VT, st, dt);
    attn_head_kernel<<<768, 256, 0, stream>>>(VT, st, dt, maskw, hacc);
    // GRU + heads
    gruheads_kernel<<<256, 256, 0, stream>>>(
        hacc, rsum, hp16, wi16, wh16, gbi, gbh, h_prev,
        Wa1T, Wc1T, ba1, Wa2, ba2, bc1, Wc2, bc2, hnew, probs, value);
}